// Round 4
// baseline (294.775 us; speedup 1.0000x reference)
//
#include <hip/hip_runtime.h>

// LSTM (B=8192, T=256, in=1, H=64) + fc1(64->32,relu) + fc2(32->2).
// Skewed dual-chain MFMA split-bf16. 256 blocks x 256 thr = 1 block/CU,
// 4 waves = 1/SIMD. Each block: two 16-batch chains A,B half-step skewed:
//   phase1: MFMA_A(t) || cell_B(t-1)->write hB   ; barrier
//   phase2: MFMA_B(t) || cell_A(t)->write hA     ; barrier
// MFMA cluster and cell update in each phase are independent -> matrix and
// VALU/trans pipes overlap statically. Single h buffer per chain (barrier-
// separated). W_hh^T hi/lo bf16 frags in regs, pre-scaled by -log2e
// (-2log2e for gate g) so each nonlinearity is rcp(1+exp2(v)).

typedef __attribute__((ext_vector_type(8))) short bf16x8;
typedef __attribute__((ext_vector_type(4))) float f32x4;

#define TT 256
#define BT 32      // 2 chains x 16
#define XPAD 260   // f32 row pad
#define HROW 72    // h row stride in bf16 (64+8) = 144B

#if __has_builtin(__builtin_amdgcn_exp2f)
#define EXP2F __builtin_amdgcn_exp2f
#else
#define EXP2F exp2f
#endif
#if __has_builtin(__builtin_amdgcn_rcpf)
#define RCPF __builtin_amdgcn_rcpf
#else
#define RCPF(x) (1.0f / (x))
#endif

#define NLOG2E  -1.4426950408889634f
#define N2LOG2E -2.8853900817779268f

__device__ __forceinline__ ushort f2bf(float f) {  // RNE f32 -> bf16 bits
    union { float f; unsigned u; } v; v.f = f;
    unsigned r = v.u + 0x7FFFu + ((v.u >> 16) & 1u);
    return (ushort)(r >> 16);
}
__device__ __forceinline__ float bf2f(ushort b) {
    union { unsigned u; float f; } v; v.u = ((unsigned)b) << 16;
    return v.f;
}
__device__ __forceinline__ float lo_as_f(unsigned pk) {
    union { unsigned u; float f; } v; v.u = pk << 16;
    return v.f;
}
__device__ __forceinline__ float hi_as_f(unsigned pk) {
    union { unsigned u; float f; } v; v.u = pk & 0xFFFF0000u;
    return v.f;
}
__device__ __forceinline__ unsigned cvt_pk(float a, float b) {
    unsigned r;
    asm("v_cvt_pk_bf16_f32 %0, %1, %2" : "=v"(r) : "v"(a), "v"(b));
    return r;
}

__global__ __launch_bounds__(256, 1) void lstm_dual(
    const float* __restrict__ x,      // [B,T]
    const float* __restrict__ W_ih,   // [256]
    const float* __restrict__ W_hh,   // [256][64]
    const float* __restrict__ b_ih,   // [256]
    const float* __restrict__ b_hh,   // [256]
    const float* __restrict__ fc1_w,  // [32][64]
    const float* __restrict__ fc1_b,  // [32]
    const float* __restrict__ fc2_w,  // [2][32]
    const float* __restrict__ fc2_b,  // [2]
    float* __restrict__ out)          // [B][2]
{
    __shared__ float  x_lds[BT][XPAD];
    __shared__ ushort hA_hi[16][HROW], hA_lo[16][HROW];
    __shared__ ushort hB_hi[16][HROW], hB_lo[16][HROW];

    const int tid  = threadIdx.x;
    const int lane = tid & 63;
    const int ub   = tid >> 6;          // wave 0..3 = unit block
    const int l15  = lane & 15;         // batch within chain; W tile row
    const int l4   = lane >> 4;         // 0..3
    const int u0   = ub * 16 + l4 * 4;  // first hidden unit this lane owns
    const long long bBase = (long long)blockIdx.x * BT;

    // ---- stage x tile via float4 (coalesced) ----
    {
        const float4* xg = (const float4*)(x + bBase * TT);
        for (int idx = tid; idx < BT * TT / 4; idx += 256) {
            int b = idx >> 6, c4 = idx & 63;
            *(float4*)&x_lds[b][c4 * 4] = xg[idx];
        }
    }
    // ---- zero h ----
    for (int idx = tid; idx < 16 * HROW; idx += 256) {
        ((ushort*)hA_hi)[idx] = 0; ((ushort*)hA_lo)[idx] = 0;
        ((ushort*)hB_hi)[idx] = 0; ((ushort*)hB_lo)[idx] = 0;
    }

    // ---- W_hh A-fragments, hi/lo bf16, pre-scaled, resident in regs ----
    // A[m][k]: m = l15 (tile row, abs gate-row g*64+ub*16+l15), k = kt*32+l4*8+j
    bf16x8 Whi[4][2], Wlo[4][2];
#pragma unroll
    for (int g = 0; g < 4; ++g) {
        const float sg = (g == 2) ? N2LOG2E : NLOG2E;
#pragma unroll
        for (int kt = 0; kt < 2; ++kt) {
            const float* src = W_hh + (g * 64 + ub * 16 + l15) * 64 + kt * 32 + l4 * 8;
#pragma unroll
            for (int j = 0; j < 8; ++j) {
                float f   = src[j] * sg;
                ushort hi = f2bf(f);
                Whi[g][kt][j] = (short)hi;
                Wlo[g][kt][j] = (short)f2bf(f - bf2f(hi));
            }
        }
    }

    // per-lane gate input weights / biases (scaled) for unit u0+j
    float wih[4][4], bias[4][4];
#pragma unroll
    for (int g = 0; g < 4; ++g) {
        const float sg = (g == 2) ? N2LOG2E : NLOG2E;
#pragma unroll
        for (int j = 0; j < 4; ++j) {
            int idx = g * 64 + u0 + j;
            wih[g][j]  = W_ih[idx] * sg;
            bias[g][j] = (b_ih[idx] + b_hh[idx]) * sg;
        }
    }

    // gates: acc = x*wih + bias + W*h (24 MFMAs, 3-term split)
    auto gates = [&](f32x4 (&acc)[4], const ushort (*hhi)[HROW],
                     const ushort (*hlo)[HROW], int xrow, int t) {
        const bf16x8 b0h = *(const bf16x8*)&hhi[l15][l4 * 8];
        const bf16x8 b1h = *(const bf16x8*)&hhi[l15][32 + l4 * 8];
        const bf16x8 b0l = *(const bf16x8*)&hlo[l15][l4 * 8];
        const bf16x8 b1l = *(const bf16x8*)&hlo[l15][32 + l4 * 8];
        const float xr = x_lds[xrow][t];
#pragma unroll
        for (int g = 0; g < 4; ++g)
#pragma unroll
            for (int j = 0; j < 4; ++j)
                acc[g][j] = xr * wih[g][j] + bias[g][j];
#pragma unroll
        for (int kt = 0; kt < 2; ++kt) {
            const bf16x8 bh = kt ? b1h : b0h;
            const bf16x8 bl = kt ? b1l : b0l;
#pragma unroll
            for (int g = 0; g < 4; ++g)
                acc[g] = __builtin_amdgcn_mfma_f32_16x16x32_bf16(Whi[g][kt], bh, acc[g], 0, 0, 0);
#pragma unroll
            for (int g = 0; g < 4; ++g)
                acc[g] = __builtin_amdgcn_mfma_f32_16x16x32_bf16(Whi[g][kt], bl, acc[g], 0, 0, 0);
#pragma unroll
            for (int g = 0; g < 4; ++g)
                acc[g] = __builtin_amdgcn_mfma_f32_16x16x32_bf16(Wlo[g][kt], bh, acc[g], 0, 0, 0);
        }
    };

    // cell: nonlinearities + c update + split-bf16 h write
    auto cell = [&](const f32x4 (&acc)[4], float (&cst)[4],
                    ushort (*hhi)[HROW], ushort (*hlo)[HROW]) {
        float hn[4];
#pragma unroll
        for (int j = 0; j < 4; ++j) {
            float iv = RCPF(1.0f + EXP2F(acc[0][j]));
            float fv = RCPF(1.0f + EXP2F(acc[1][j]));
            float gv = 2.0f * RCPF(1.0f + EXP2F(acc[2][j])) - 1.0f;
            float ov = RCPF(1.0f + EXP2F(acc[3][j]));
            float cc = fv * cst[j] + iv * gv;
            cst[j]   = cc;
            float th = 2.0f * RCPF(1.0f + EXP2F(N2LOG2E * cc)) - 1.0f;
            hn[j]    = ov * th;
        }
        unsigned hi01 = cvt_pk(hn[0], hn[1]);
        unsigned hi23 = cvt_pk(hn[2], hn[3]);
        unsigned lo01 = cvt_pk(hn[0] - lo_as_f(hi01), hn[1] - hi_as_f(hi01));
        unsigned lo23 = cvt_pk(hn[2] - lo_as_f(hi23), hn[3] - hi_as_f(hi23));
        *(uint2*)&hhi[l15][u0] = make_uint2(hi01, hi23);
        *(uint2*)&hlo[l15][u0] = make_uint2(lo01, lo23);
    };

    f32x4 accA[4], accB[4];
    float cstA[4] = {0.f, 0.f, 0.f, 0.f};
    float cstB[4] = {0.f, 0.f, 0.f, 0.f};

    __syncthreads();

#pragma unroll 1
    for (int t = 0; t < TT; ++t) {
        // phase 1: gates A(t)  ||  finish B(t-1)
        gates(accA, hA_hi, hA_lo, l15, t);
        if (t > 0) cell(accB, cstB, hB_hi, hB_lo);
        __syncthreads();
        // phase 2: gates B(t)  ||  finish A(t)
        gates(accB, hB_hi, hB_lo, 16 + l15, t);
        cell(accA, cstA, hA_hi, hA_lo);
        __syncthreads();
    }
    cell(accB, cstB, hB_hi, hB_lo);   // finish B(255)
    __syncthreads();

    // ---- tail: fc1 + relu into x_lds (x dead), then fc2 ----
    {
        const int b = tid >> 3, part = tid & 7;
        const int br = b & 15;
        const ushort (*Hh)[HROW] = (b < 16) ? hA_hi : hB_hi;
        const ushort (*Hl)[HROW] = (b < 16) ? hA_lo : hB_lo;
#pragma unroll
        for (int q = 0; q < 4; ++q) {
            const int u2 = part * 4 + q;
            float a = fc1_b[u2];
            for (int k = 0; k < 64; ++k)
                a += fc1_w[u2 * 64 + k] * (bf2f(Hh[br][k]) + bf2f(Hl[br][k]));
            x_lds[b][u2] = a > 0.0f ? a : 0.0f;
        }
    }
    __syncthreads();
    if (tid < BT * 2) {
        const int b = tid >> 1, o = tid & 1;
        float a = fc2_b[o];
#pragma unroll
        for (int u2 = 0; u2 < 32; ++u2)
            a += x_lds[b][u2] * fc2_w[o * 32 + u2];
        out[(bBase + b) * 2 + o] = a;
    }
}

extern "C" void kernel_launch(void* const* d_in, const int* in_sizes, int n_in,
                              void* d_out, int out_size, void* d_ws, size_t ws_size,
                              hipStream_t stream) {
    const float* x     = (const float*)d_in[0];
    const float* W_ih  = (const float*)d_in[1];
    const float* W_hh  = (const float*)d_in[2];
    const float* b_ih  = (const float*)d_in[3];
    const float* b_hh  = (const float*)d_in[4];
    const float* fc1_w = (const float*)d_in[5];
    const float* fc1_b = (const float*)d_in[6];
    const float* fc2_w = (const float*)d_in[7];
    const float* fc2_b = (const float*)d_in[8];
    float* out = (float*)d_out;

    lstm_dual<<<dim3(8192 / BT), dim3(256), 0, stream>>>(
        x, W_ih, W_hh, b_ih, b_hh, fc1_w, fc1_b, fc2_w, fc2_b, out);
}

// Round 6
// 252.084 us; speedup vs baseline: 1.1694x; 1.1694x over previous
//
#include <hip/hip_runtime.h>

// LSTM (B=8192, T=256, in=1, H=64) + fc1(64->32,relu) + fc2(32->2).
// 8-wave split-bf16 MFMA with unit-major gate packing.
// 512 blocks x 512 thr (8 waves) = 2 blocks/CU, 4 waves/SIMD from 2
// independent barrier groups. W_hh rows permuted to row = unit*4 + gate so a
// 16-row C-tile = 4 units x 4 gates and C/D layout (row = l4*4 + reg) gives
// reg == gate: each lane owns complete cells. Wave w owns tiles 2w,2w+1
// (units 8w..8w+8): 12 MFMAs/step, 2 cells/lane. W hi/lo frags in regs
// (pre-scaled by -log2e, -2log2e for gate g); h hi/lo bf16 planes in LDS,
// double-buffered, 1 barrier/step.

typedef __attribute__((ext_vector_type(8))) short bf16x8;
typedef __attribute__((ext_vector_type(4))) float f32x4;

#define TT 256
#define BT 16
#define XPAD 260   // f32 row pad
#define HROW 72    // h row stride in bf16 (64+8) = 144B, 16B-aligned

#if __has_builtin(__builtin_amdgcn_exp2f)
#define EXP2F __builtin_amdgcn_exp2f
#else
#define EXP2F exp2f
#endif
#if __has_builtin(__builtin_amdgcn_rcpf)
#define RCPF __builtin_amdgcn_rcpf
#else
#define RCPF(x) (1.0f / (x))
#endif

#define NLOG2E  -1.4426950408889634f
#define N2LOG2E -2.8853900817779268f

__device__ __forceinline__ ushort f2bf(float f) {  // RNE f32 -> bf16 bits
    union { float f; unsigned u; } v; v.f = f;
    unsigned r = v.u + 0x7FFFu + ((v.u >> 16) & 1u);
    return (ushort)(r >> 16);
}
__device__ __forceinline__ float bf2f(ushort b) {
    union { unsigned u; float f; } v; v.u = ((unsigned)b) << 16;
    return v.f;
}
__device__ __forceinline__ float lo_as_f(unsigned pk) {
    union { unsigned u; float f; } v; v.u = pk << 16;
    return v.f;
}
__device__ __forceinline__ float hi_as_f(unsigned pk) {
    union { unsigned u; float f; } v; v.u = pk & 0xFFFF0000u;
    return v.f;
}
__device__ __forceinline__ unsigned cvt_pk(float a, float b) {
    unsigned r;
    asm("v_cvt_pk_bf16_f32 %0, %1, %2" : "=v"(r) : "v"(a), "v"(b));
    return r;
}

__global__ __launch_bounds__(512, 4) void lstm_w8(
    const float* __restrict__ x,      // [B,T]
    const float* __restrict__ W_ih,   // [256]
    const float* __restrict__ W_hh,   // [256][64]
    const float* __restrict__ b_ih,   // [256]
    const float* __restrict__ b_hh,   // [256]
    const float* __restrict__ fc1_w,  // [32][64]
    const float* __restrict__ fc1_b,  // [32]
    const float* __restrict__ fc2_w,  // [2][32]
    const float* __restrict__ fc2_b,  // [2]
    float* __restrict__ out)          // [B][2]
{
    __shared__ float  x_lds[BT][XPAD];
    __shared__ ushort h_hi[2][BT][HROW];
    __shared__ ushort h_lo[2][BT][HROW];

    const int tid  = threadIdx.x;
    const int lane = tid & 63;
    const int w    = tid >> 6;       // wave 0..7 -> tiles 2w, 2w+1
    const int l15  = lane & 15;      // batch (C col / B-frag n); A-frag row
    const int l4   = lane >> 4;      // 0..3
    const int gate = l15 & 3;        // A-frag: permuted-row gate
    const int urow = l15 >> 2;       // A-frag: permuted-row unit sub-index
    const long long bBase = (long long)blockIdx.x * BT;

    // ---- stage x tile via float4 (coalesced) ----
    {
        const float4* xg = (const float4*)(x + bBase * TT);
        for (int idx = tid; idx < BT * TT / 4; idx += 512) {
            int b = idx >> 6, c4 = idx & 63;
            *(float4*)&x_lds[b][c4 * 4] = xg[idx];
        }
    }
    // ---- zero h buffer 0 ----
    for (int idx = tid; idx < BT * HROW; idx += 512) {
        ((ushort*)h_hi[0])[idx] = 0;
        ((ushort*)h_lo[0])[idx] = 0;
    }

    // ---- W_hh A-fragments (unit-major permuted rows), hi/lo, pre-scaled ----
    // Tile t = 2w+tt covers permuted rows t*16..+16; lane row m=l15 ->
    // unit = t*4 + (l15>>2), gate = l15&3. k = kt*32 + l4*8 + j.
    const float sgA = (gate == 2) ? N2LOG2E : NLOG2E;
    bf16x8 Whi[2][2], Wlo[2][2];
#pragma unroll
    for (int tt = 0; tt < 2; ++tt)
#pragma unroll
        for (int kt = 0; kt < 2; ++kt) {
            const int unit = (2 * w + tt) * 4 + urow;
            const float* src = W_hh + (gate * 64 + unit) * 64 + kt * 32 + l4 * 8;
#pragma unroll
            for (int j = 0; j < 8; ++j) {
                float f   = src[j] * sgA;
                ushort hi = f2bf(f);
                Whi[tt][kt][j] = (short)hi;
                Wlo[tt][kt][j] = (short)f2bf(f - bf2f(hi));
            }
        }

    // ---- per-lane cell params: cell (b=l15, u = (2w+tt)*4 + l4), gates 0..3
    float wih[2][4], bias[2][4];
#pragma unroll
    for (int tt = 0; tt < 2; ++tt) {
        const int u = (2 * w + tt) * 4 + l4;
#pragma unroll
        for (int g = 0; g < 4; ++g) {
            const float sg = (g == 2) ? N2LOG2E : NLOG2E;
            const int idx = g * 64 + u;
            wih[tt][g]  = W_ih[idx] * sg;
            bias[tt][g] = (b_ih[idx] + b_hh[idx]) * sg;
        }
    }

    const int uA = 8 * w + l4;       // cell-A unit, cell-B = uA + 4
    float cst[2] = {0.f, 0.f};
    __syncthreads();

    int p = 0;
#pragma unroll 1
    for (int t = 0; t < TT; ++t) {
        // B-fragments (h^T): pre-packed bf16 hi/lo from LDS
        const bf16x8 b0h = *(const bf16x8*)&h_hi[p][l15][l4 * 8];
        const bf16x8 b1h = *(const bf16x8*)&h_hi[p][l15][32 + l4 * 8];
        const bf16x8 b0l = *(const bf16x8*)&h_lo[p][l15][l4 * 8];
        const bf16x8 b1l = *(const bf16x8*)&h_lo[p][l15][32 + l4 * 8];
        const float xr = x_lds[l15][t];

        f32x4 acc[2];
#pragma unroll
        for (int tt = 0; tt < 2; ++tt)
#pragma unroll
            for (int g = 0; g < 4; ++g)
                acc[tt][g] = xr * wih[tt][g] + bias[tt][g];

        // 12 MFMAs: Whi*hhi + Whi*hlo + Wlo*hhi, 2 tile-chains interleaved
#pragma unroll
        for (int kt = 0; kt < 2; ++kt) {
            const bf16x8 bh = kt ? b1h : b0h;
            const bf16x8 bl = kt ? b1l : b0l;
            acc[0] = __builtin_amdgcn_mfma_f32_16x16x32_bf16(Whi[0][kt], bh, acc[0], 0, 0, 0);
            acc[1] = __builtin_amdgcn_mfma_f32_16x16x32_bf16(Whi[1][kt], bh, acc[1], 0, 0, 0);
            acc[0] = __builtin_amdgcn_mfma_f32_16x16x32_bf16(Whi[0][kt], bl, acc[0], 0, 0, 0);
            acc[1] = __builtin_amdgcn_mfma_f32_16x16x32_bf16(Whi[1][kt], bl, acc[1], 0, 0, 0);
            acc[0] = __builtin_amdgcn_mfma_f32_16x16x32_bf16(Wlo[0][kt], bh, acc[0], 0, 0, 0);
            acc[1] = __builtin_amdgcn_mfma_f32_16x16x32_bf16(Wlo[1][kt], bh, acc[1], 0, 0, 0);
        }

        // cell updates (gate order i,f,g,o == acc regs 0..3)
        float hn[2];
#pragma unroll
        for (int tt = 0; tt < 2; ++tt) {
            float iv = RCPF(1.0f + EXP2F(acc[tt][0]));
            float fv = RCPF(1.0f + EXP2F(acc[tt][1]));
            float gv = 2.0f * RCPF(1.0f + EXP2F(acc[tt][2])) - 1.0f;
            float ov = RCPF(1.0f + EXP2F(acc[tt][3]));
            float cc = fv * cst[tt] + iv * gv;
            cst[tt]  = cc;
            hn[tt]   = ov * (2.0f * RCPF(1.0f + EXP2F(N2LOG2E * cc)) - 1.0f);
        }

        // split-bf16 h write (scattered b16: units uA, uA+4)
        unsigned ph = cvt_pk(hn[0], hn[1]);
        unsigned pl = cvt_pk(hn[0] - lo_as_f(ph), hn[1] - hi_as_f(ph));
        const int q = p ^ 1;
        h_hi[q][l15][uA]     = (ushort)ph;
        h_hi[q][l15][uA + 4] = (ushort)(ph >> 16);
        h_lo[q][l15][uA]     = (ushort)pl;
        h_lo[q][l15][uA + 4] = (ushort)(pl >> 16);

        __syncthreads();
        p = q;
    }

    // ---- tail: fc1 + relu into x_lds (x dead), then fc2 ----
    {
        const int b = tid >> 5, u2 = tid & 31;   // 512 = 16 x 32
        float a = fc1_b[u2];
        for (int k = 0; k < 64; ++k)
            a += fc1_w[u2 * 64 + k] * (bf2f(h_hi[p][b][k]) + bf2f(h_lo[p][b][k]));
        x_lds[b][u2] = a > 0.0f ? a : 0.0f;
    }
    __syncthreads();
    if (tid < BT * 2) {
        const int b = tid >> 1, o = tid & 1;
        float a = fc2_b[o];
#pragma unroll
        for (int u2 = 0; u2 < 32; ++u2)
            a += x_lds[b][u2] * fc2_w[o * 32 + u2];
        out[(bBase + b) * 2 + o] = a;
    }
}

extern "C" void kernel_launch(void* const* d_in, const int* in_sizes, int n_in,
                              void* d_out, int out_size, void* d_ws, size_t ws_size,
                              hipStream_t stream) {
    const float* x     = (const float*)d_in[0];
    const float* W_ih  = (const float*)d_in[1];
    const float* W_hh  = (const float*)d_in[2];
    const float* b_ih  = (const float*)d_in[3];
    const float* b_hh  = (const float*)d_in[4];
    const float* fc1_w = (const float*)d_in[5];
    const float* fc1_b = (const float*)d_in[6];
    const float* fc2_w = (const float*)d_in[7];
    const float* fc2_b = (const float*)d_in[8];
    float* out = (float*)d_out;

    lstm_w8<<<dim3(8192 / BT), dim3(512), 0, stream>>>(
        x, W_ih, W_hh, b_ih, b_hh, fc1_w, fc1_b, fc2_w, fc2_b, out);
}

// Round 8
// 229.473 us; speedup vs baseline: 1.2846x; 1.0985x over previous
//
#include <hip/hip_runtime.h>

// LSTM (B=8192, T=256, in=1, H=64) + fc1(64->32,relu) + fc2(32->2).
// Trans-minimized split-bf16 MFMA. 512 blocks x 1024 thr (16 waves) = 2
// blocks/CU -> 8 waves/SIMD. Wave w owns ONE 16-row C-tile (unit-major gate
// packing: permuted row = unit*4+gate), lane owns cell (b=lane&15, u=4w+l4),
// gates in acc[0..3]. 6 MFMAs/wave/step (3-term split, K=64).
// h hi/lo bf16 planes in LDS: 128B rows, 16B-block XOR swizzle (blk ^= row&7)
// -> all reads/writes <=2-way bank (free). Cell math via common denominator:
// 5 exp2 + 2 rcp per cell (was 10 trans) -- the kernel is trans-issue-bound.

typedef __attribute__((ext_vector_type(8))) short bf16x8;
typedef __attribute__((ext_vector_type(4))) float f32x4;

#define TT 256
#define BT 16
#define XPAD 260

#if __has_builtin(__builtin_amdgcn_exp2f)
#define EXP2F __builtin_amdgcn_exp2f
#else
#define EXP2F exp2f
#endif
#if __has_builtin(__builtin_amdgcn_rcpf)
#define RCPF __builtin_amdgcn_rcpf
#else
#define RCPF(x) (1.0f / (x))
#endif

#define NLOG2E  -1.4426950408889634f
#define N2LOG2E -2.8853900817779268f

__device__ __forceinline__ ushort f2bf(float f) {  // RNE f32 -> bf16 bits
    union { float f; unsigned u; } v; v.f = f;
    unsigned r = v.u + 0x7FFFu + ((v.u >> 16) & 1u);
    return (ushort)(r >> 16);
}
__device__ __forceinline__ float bf2f(ushort b) {
    union { unsigned u; float f; } v; v.u = ((unsigned)b) << 16;
    return v.f;
}
__device__ __forceinline__ float lo_as_f(unsigned pk) {
    union { unsigned u; float f; } v; v.u = pk << 16;
    return v.f;
}
__device__ __forceinline__ unsigned cvt_pk(float a, float b) {
    unsigned r;
    asm("v_cvt_pk_bf16_f32 %0, %1, %2" : "=v"(r) : "v"(a), "v"(b));
    return r;
}

__global__ __launch_bounds__(1024, 8) void lstm_w16(
    const float* __restrict__ x,      // [B,T]
    const float* __restrict__ W_ih,   // [256]
    const float* __restrict__ W_hh,   // [256][64]
    const float* __restrict__ b_ih,   // [256]
    const float* __restrict__ b_hh,   // [256]
    const float* __restrict__ fc1_w,  // [32][64]
    const float* __restrict__ fc1_b,  // [32]
    const float* __restrict__ fc2_w,  // [2][32]
    const float* __restrict__ fc2_b,  // [2]
    float* __restrict__ out)          // [B][2]
{
    __shared__ float  x_lds[BT][XPAD];
    __shared__ ushort h_hi[2][BT * 64];   // 128B rows, XOR-swizzled 16B blocks
    __shared__ ushort h_lo[2][BT * 64];

    const int tid  = threadIdx.x;
    const int lane = tid & 63;
    const int w    = tid >> 6;       // wave 0..15 = C-tile index
    const int l15  = lane & 15;      // batch (C col / B-frag n); A-frag row
    const int l4   = lane >> 4;      // 0..3
    const int s7   = l15 & 7;        // swizzle key (row)
    const long long bBase = (long long)blockIdx.x * BT;

    // ---- stage x tile: exactly 1024 float4s, one per thread ----
    {
        const float4* xg = (const float4*)(x + bBase * TT);
        const int b = tid >> 6, c4 = tid & 63;
        *(float4*)&x_lds[b][c4 * 4] = xg[tid];
    }
    // ---- zero h buffer 0: exactly 1024 ushorts per plane ----
    h_hi[0][tid] = 0;
    h_lo[0][tid] = 0;

    // ---- W_hh A-fragments (unit-major permuted rows), hi/lo, pre-scaled ----
    // Tile w, lane row m=l15 -> unit = w*4 + (l15>>2), gate = l15&3.
    const int gate = l15 & 3;
    const int um   = w * 4 + (l15 >> 2);
    const float sgA = (gate == 2) ? N2LOG2E : NLOG2E;
    bf16x8 Whi[2], Wlo[2];
#pragma unroll
    for (int kt = 0; kt < 2; ++kt) {
        const float* src = W_hh + (gate * 64 + um) * 64 + kt * 32 + l4 * 8;
#pragma unroll
        for (int j = 0; j < 8; ++j) {
            float f   = src[j] * sgA;
            ushort hi = f2bf(f);
            Whi[kt][j] = (short)hi;
            Wlo[kt][j] = (short)f2bf(f - bf2f(hi));
        }
    }

    // ---- per-lane cell params: cell (b=l15, u = 4w + l4), gates 0..3 ----
    const int u = 4 * w + l4;
    float wih[4], bias[4];
#pragma unroll
    for (int g = 0; g < 4; ++g) {
        const float sg = (g == 2) ? N2LOG2E : NLOG2E;
        const int idx = g * 64 + u;
        wih[g]  = W_ih[idx] * sg;
        bias[g] = (b_ih[idx] + b_hh[idx]) * sg;
    }

    // ---- swizzled LDS offsets (ushort units), loop-invariant ----
    const int ro = l15 * 64;                       // row base
    const int b0 = l4 ^ s7;                        // k-half-0 block
    const int o0 = ro + b0 * 8;                    // read: blocks b0, b0^4
    const int o1 = ro + (b0 ^ 4) * 8;
    const int wo = ro + (((w >> 1) ^ s7) << 3) + ((w & 1) << 2) + l4;  // write

    float cst = 0.0f;
    __syncthreads();

    // one LSTM step at compile-time-constant buffer p
    auto step = [&](int p, int t) {
        const bf16x8 bh0 = *(const bf16x8*)&h_hi[p][o0];
        const bf16x8 bh1 = *(const bf16x8*)&h_hi[p][o1];
        const bf16x8 bl0 = *(const bf16x8*)&h_lo[p][o0];
        const bf16x8 bl1 = *(const bf16x8*)&h_lo[p][o1];
        const float xr = x_lds[l15][t];

        f32x4 acc;
#pragma unroll
        for (int g = 0; g < 4; ++g) acc[g] = xr * wih[g] + bias[g];

        acc = __builtin_amdgcn_mfma_f32_16x16x32_bf16(Whi[0], bh0, acc, 0, 0, 0);
        acc = __builtin_amdgcn_mfma_f32_16x16x32_bf16(Whi[1], bh1, acc, 0, 0, 0);
        acc = __builtin_amdgcn_mfma_f32_16x16x32_bf16(Whi[0], bl0, acc, 0, 0, 0);
        acc = __builtin_amdgcn_mfma_f32_16x16x32_bf16(Whi[1], bl1, acc, 0, 0, 0);
        acc = __builtin_amdgcn_mfma_f32_16x16x32_bf16(Wlo[0], bh0, acc, 0, 0, 0);
        acc = __builtin_amdgcn_mfma_f32_16x16x32_bf16(Wlo[1], bh1, acc, 0, 0, 0);

        // cell update, common-denominator form (i,f,g,o = acc 0..3, pre-scaled):
        // A=e^-pi F=e^-pf B=e^-2pg C=e^-po
        // cc = [c(1+A)(1+B) + (1-B)(1+F)] / [(1+F)(1+A)(1+B)]
        // hn = (1-D)/[(1+C)(1+D)],  D = e^-2cc
        const float A  = EXP2F(acc[0]);
        const float F  = EXP2F(acc[1]);
        const float Bv = EXP2F(acc[2]);
        const float C  = EXP2F(acc[3]);
        const float pA = 1.0f + A, pF = 1.0f + F, pB = 1.0f + Bv, pC = 1.0f + C;
        const float P   = pA * pB;
        const float den = P * pF;
        const float num = cst * P + (1.0f - Bv) * pF;
        const float cc  = num * RCPF(den);
        cst = cc;
        float targ = N2LOG2E * cc;
        targ = fminf(fmaxf(targ, -60.0f), 60.0f);   // avoid Inf/Inf -> NaN
        const float D  = EXP2F(targ);
        const float hn = (1.0f - D) * RCPF(pC * (1.0f + D));

        // split-bf16 write (2 x ds_write_b16, 2-way max with swizzle)
        const unsigned ph = cvt_pk(hn, hn);
        const unsigned pl = cvt_pk(hn - lo_as_f(ph), hn - lo_as_f(ph));
        h_hi[p ^ 1][wo] = (ushort)ph;
        h_lo[p ^ 1][wo] = (ushort)pl;
        __syncthreads();
    };

#pragma unroll 1
    for (int t = 0; t < TT; t += 2) {
        step(0, t);       // reads buf0, writes buf1
        step(1, t + 1);   // reads buf1, writes buf0
    }
    // final h is in buffer 0

    // ---- tail: fc1 + relu into x_lds (x dead), then fc2 ----
    if (tid < BT * 32) {
        const int b = tid >> 5, u2 = tid & 31;
        float a = fc1_b[u2];
        for (int k = 0; k < 64; ++k) {
            const int off = b * 64 + ((((k >> 3) ^ (b & 7))) << 3) + (k & 7);
            a += fc1_w[u2 * 64 + k] * (bf2f(h_hi[0][off]) + bf2f(h_lo[0][off]));
        }
        x_lds[b][u2] = a > 0.0f ? a : 0.0f;
    }
    __syncthreads();
    if (tid < BT * 2) {
        const int b = tid >> 1, o = tid & 1;
        float a = fc2_b[o];
#pragma unroll
        for (int u2 = 0; u2 < 32; ++u2)
            a += x_lds[b][u2] * fc2_w[o * 32 + u2];
        out[(bBase + b) * 2 + o] = a;
    }
}

extern "C" void kernel_launch(void* const* d_in, const int* in_sizes, int n_in,
                              void* d_out, int out_size, void* d_ws, size_t ws_size,
                              hipStream_t stream) {
    const float* x     = (const float*)d_in[0];
    const float* W_ih  = (const float*)d_in[1];
    const float* W_hh  = (const float*)d_in[2];
    const float* b_ih  = (const float*)d_in[3];
    const float* b_hh  = (const float*)d_in[4];
    const float* fc1_w = (const float*)d_in[5];
    const float* fc1_b = (const float*)d_in[6];
    const float* fc2_w = (const float*)d_in[7];
    const float* fc2_b = (const float*)d_in[8];
    float* out = (float*)d_out;

    lstm_w16<<<dim3(8192 / BT), dim3(1024), 0, stream>>>(
        x, W_ih, W_hh, b_ih, b_hh, fc1_w, fc1_b, fc2_w, fc2_b, out);
}

// Round 9
// 160.536 us; speedup vs baseline: 1.8362x; 1.4294x over previous
//
#include <hip/hip_runtime.h>

// LSTM (B=8192, T=256, in=1, H=64) + fc1(64->32,relu) + fc2(32->2).
// fp16 single-plane MFMA. 512 blocks x 1024 thr (16 waves) = 2 blocks/CU ->
// 8 waves/SIMD. Wave w owns one 16-row C-tile (unit-major gate packing:
// permuted row = unit*4+gate), lane owns cell (b=lane&15, u=4w+l4), gates in
// acc[0..3]. h stored as ONE fp16 plane (h in (-1,1): fp16 2^-12 rounding
// beats bf16-hi 2^-9; no hi/lo split needed) -> 2 ds_read_b128 + 2 MFMAs
// (16x16x32_f16) per wave-step, 1 ds_write_b16. 128B rows, 16B-block XOR
// swizzle (blk ^= row&7). Cell: common-denominator form, 5 exp2 + 2 rcp.
// Trans pipe is the floor: 7 trans x 16cy x 8 waves = 896 cy/SIMD/step.

typedef __attribute__((ext_vector_type(8))) _Float16 f16x8;
typedef __attribute__((ext_vector_type(4))) float f32x4;

#define TT 256
#define BT 16
#define XPAD 260

#if __has_builtin(__builtin_amdgcn_exp2f)
#define EXP2F __builtin_amdgcn_exp2f
#else
#define EXP2F exp2f
#endif
#if __has_builtin(__builtin_amdgcn_rcpf)
#define RCPF __builtin_amdgcn_rcpf
#else
#define RCPF(x) (1.0f / (x))
#endif
#if __has_builtin(__builtin_amdgcn_fmed3f)
#define MED3F __builtin_amdgcn_fmed3f
#else
#define MED3F(a, lo, hi) fminf(fmaxf((a), (lo)), (hi))
#endif

#define NLOG2E  -1.4426950408889634f
#define N2LOG2E -2.8853900817779268f

__device__ __forceinline__ ushort f2h_bits(float f) {
    union { _Float16 h; ushort u; } v;
    v.h = (_Float16)f;
    return v.u;
}
__device__ __forceinline__ float h2f(ushort u) {
    union { ushort u; _Float16 h; } v;
    v.u = u;
    return (float)v.h;
}

__global__ __launch_bounds__(1024, 8) void lstm_h16(
    const float* __restrict__ x,      // [B,T]
    const float* __restrict__ W_ih,   // [256]
    const float* __restrict__ W_hh,   // [256][64]
    const float* __restrict__ b_ih,   // [256]
    const float* __restrict__ b_hh,   // [256]
    const float* __restrict__ fc1_w,  // [32][64]
    const float* __restrict__ fc1_b,  // [32]
    const float* __restrict__ fc2_w,  // [2][32]
    const float* __restrict__ fc2_b,  // [2]
    float* __restrict__ out)          // [B][2]
{
    __shared__ float  x_lds[BT][XPAD];
    __shared__ ushort h_pl[2][BT * 64];   // fp16 plane, 128B rows, XOR-swizzled 16B blocks

    const int tid  = threadIdx.x;
    const int lane = tid & 63;
    const int w    = tid >> 6;       // wave 0..15 = C-tile index
    const int l15  = lane & 15;      // batch (C col / B-frag n); A-frag row
    const int l4   = lane >> 4;      // 0..3
    const int s7   = l15 & 7;        // swizzle key (row)
    const long long bBase = (long long)blockIdx.x * BT;

    // ---- stage x tile: exactly 1024 float4s, one per thread ----
    {
        const float4* xg = (const float4*)(x + bBase * TT);
        const int b = tid >> 6, c4 = tid & 63;
        *(float4*)&x_lds[b][c4 * 4] = xg[tid];
    }
    // ---- zero h buffer 0: exactly 1024 ushorts ----
    h_pl[0][tid] = 0;

    // ---- W_hh A-fragments (unit-major permuted rows), fp16, pre-scaled ----
    // Tile w, lane row m=l15 -> unit = w*4 + (l15>>2), gate = l15&3.
    const int gate = l15 & 3;
    const int um   = w * 4 + (l15 >> 2);
    const float sgA = (gate == 2) ? N2LOG2E : NLOG2E;
    f16x8 Wf[2];
#pragma unroll
    for (int kt = 0; kt < 2; ++kt) {
        const float* src = W_hh + (gate * 64 + um) * 64 + kt * 32 + l4 * 8;
#pragma unroll
        for (int j = 0; j < 8; ++j)
            Wf[kt][j] = (_Float16)(src[j] * sgA);
    }

    // ---- per-lane cell params: cell (b=l15, u = 4w + l4), gates 0..3 ----
    const int u = 4 * w + l4;
    float wih[4], bias[4];
#pragma unroll
    for (int g = 0; g < 4; ++g) {
        const float sg = (g == 2) ? N2LOG2E : NLOG2E;
        const int idx = g * 64 + u;
        wih[g]  = W_ih[idx] * sg;
        bias[g] = (b_ih[idx] + b_hh[idx]) * sg;
    }

    // ---- swizzled LDS offsets (ushort units), loop-invariant ----
    const int ro = l15 * 64;                       // row base
    const int b0 = l4 ^ s7;                        // k-half-0 block
    const int o0 = ro + b0 * 8;                    // read: blocks b0, b0^4
    const int o1 = ro + (b0 ^ 4) * 8;
    const int wo = ro + (((w >> 1) ^ s7) << 3) + ((w & 1) << 2) + l4;  // write

    float cst = 0.0f;
    __syncthreads();

    // one LSTM step at compile-time-constant buffer p
    auto step = [&](int p, int t) {
        const f16x8 bh0 = *(const f16x8*)&h_pl[p][o0];
        const f16x8 bh1 = *(const f16x8*)&h_pl[p][o1];
        const float xr = x_lds[l15][t];

        f32x4 acc;
#pragma unroll
        for (int g = 0; g < 4; ++g) acc[g] = xr * wih[g] + bias[g];

        acc = __builtin_amdgcn_mfma_f32_16x16x32_f16(Wf[0], bh0, acc, 0, 0, 0);
        acc = __builtin_amdgcn_mfma_f32_16x16x32_f16(Wf[1], bh1, acc, 0, 0, 0);

        // cell update, common-denominator form (i,f,g,o = acc 0..3, pre-scaled):
        // A=e^-pi F=e^-pf B=e^-2pg C=e^-po
        // cc = [c(1+A)(1+B) + (1-B)(1+F)] / [(1+F)(1+A)(1+B)]
        // hn = (1-D)/[(1+C)(1+D)],  D = e^-2cc
        const float A  = EXP2F(acc[0]);
        const float F  = EXP2F(acc[1]);
        const float Bv = EXP2F(acc[2]);
        const float C  = EXP2F(acc[3]);
        const float pA = 1.0f + A, pF = 1.0f + F, pB = 1.0f + Bv, pC = 1.0f + C;
        const float P   = pA * pB;
        const float den = P * pF;
        const float num = cst * P + (1.0f - Bv) * pF;
        const float cc  = num * RCPF(den);
        cst = cc;
        const float targ = MED3F(N2LOG2E * cc, -60.0f, 60.0f);  // avoid Inf/Inf
        const float D  = EXP2F(targ);
        const float hn = (1.0f - D) * RCPF(pC * (1.0f + D));

        h_pl[p ^ 1][wo] = f2h_bits(hn);   // single fp16 write
        __syncthreads();
    };

#pragma unroll 1
    for (int t = 0; t < TT; t += 2) {
        step(0, t);       // reads buf0, writes buf1
        step(1, t + 1);   // reads buf1, writes buf0
    }
    // final h is in buffer 0

    // ---- tail: fc1 + relu into x_lds (x dead), then fc2 ----
    if (tid < BT * 32) {
        const int b = tid >> 5, u2 = tid & 31;
        float a = fc1_b[u2];
        for (int k = 0; k < 64; ++k) {
            const int off = b * 64 + ((((k >> 3) ^ (b & 7))) << 3) + (k & 7);
            a += fc1_w[u2 * 64 + k] * h2f(h_pl[0][off]);
        }
        x_lds[b][u2] = a > 0.0f ? a : 0.0f;
    }
    __syncthreads();
    if (tid < BT * 2) {
        const int b = tid >> 1, o = tid & 1;
        float a = fc2_b[o];
#pragma unroll
        for (int u2 = 0; u2 < 32; ++u2)
            a += x_lds[b][u2] * fc2_w[o * 32 + u2];
        out[(bBase + b) * 2 + o] = a;
    }
}

extern "C" void kernel_launch(void* const* d_in, const int* in_sizes, int n_in,
                              void* d_out, int out_size, void* d_ws, size_t ws_size,
                              hipStream_t stream) {
    const float* x     = (const float*)d_in[0];
    const float* W_ih  = (const float*)d_in[1];
    const float* W_hh  = (const float*)d_in[2];
    const float* b_ih  = (const float*)d_in[3];
    const float* b_hh  = (const float*)d_in[4];
    const float* fc1_w = (const float*)d_in[5];
    const float* fc1_b = (const float*)d_in[6];
    const float* fc2_w = (const float*)d_in[7];
    const float* fc2_b = (const float*)d_in[8];
    float* out = (float*)d_out;

    lstm_h16<<<dim3(8192 / BT), dim3(1024), 0, stream>>>(
        x, W_ih, W_hh, b_ih, b_hh, fc1_w, fc1_b, fc2_w, fc2_b, out);
}